// Round 19
// baseline (8480.566 us; speedup 1.0000x reference)
//
#include <hip/hip_runtime.h>
#include <stdint.h>

#define TT 2048
#define DD 2048
#define HH 16
#define HDIM 128
#define NE 8
#define TOPK 2
#define FF 1408
#define FSS 5632
#define NL 2

typedef __bf16 bf16;
typedef __bf16 bf16x2 __attribute__((ext_vector_type(2)));
typedef __bf16 bf16x4 __attribute__((ext_vector_type(4)));
typedef __bf16 bf16x8 __attribute__((ext_vector_type(8)));
typedef float f32x4 __attribute__((ext_vector_type(4)));

__device__ __forceinline__ void split1(float f, bf16& h, bf16& l) {
  bf16 hb = (bf16)f;
  h = hb;
  l = (bf16)(f - (float)hb);
}

__device__ __forceinline__ void gload16(const void* g, void* l) {
  __builtin_amdgcn_global_load_lds((const __attribute__((address_space(1))) void*)g,
                                   (__attribute__((address_space(3))) void*)l, 16, 0, 0);
}

// ------------------------------------------------ weight transpose+convert --
// W f32 [Kd][N] (N contiguous) -> planes bf16 [Ntot][Kd] at column offset nofs.
template<bool LO>
__launch_bounds__(256)
__global__ void k_wtrans(const float* __restrict__ W, bf16* __restrict__ Wh,
                         bf16* __restrict__ Wl, int Kd, int N, int nofs, int Ntot)
{
  __shared__ float T[64][68];
  const size_t slabIn  = (size_t)blockIdx.z * (size_t)Kd * (size_t)N;
  const size_t slabOut = (size_t)blockIdx.z * (size_t)Kd * (size_t)Ntot;
  const float* Wp = W + slabIn;
  const int k0 = blockIdx.x * 64, n0 = blockIdx.y * 64;
  const int tid = threadIdx.x;
  const int rr = tid >> 2, c4 = (tid & 3) * 4;
  const float* src = Wp + (size_t)(k0 + rr) * N + n0 + c4;
#pragma unroll
  for (int j = 0; j < 4; ++j) {
    f32x4 v = *(const f32x4*)(src + j * 16);
    *(f32x4*)&T[rr][c4 + j * 16] = v;
  }
  __syncthreads();
  const int nn = tid >> 2, kk = (tid & 3) * 16;
  bf16x8 h0, h1, l0, l1;
#pragma unroll
  for (int j = 0; j < 8; ++j) {
    bf16 hb, lb;
    split1(T[kk + j][nn], hb, lb);
    h0[j] = hb; l0[j] = lb;
    split1(T[kk + 8 + j][nn], hb, lb);
    h1[j] = hb; l1[j] = lb;
  }
  size_t out = slabOut + (size_t)(nofs + n0 + nn) * Kd + k0 + kk;
  *(bf16x8*)&Wh[out] = h0;
  *(bf16x8*)&Wh[out + 8] = h1;
  if (LO) {
    *(bf16x8*)&Wl[out] = l0;
    *(bf16x8*)&Wl[out + 8] = l1;
  }
}

// ----------------------------------------------------- planar bf16 GEMM -----
// C[M,N] = (Ah+Al)[M,K] @ (Bh+Bl)[N,K]^T, NT=3: hh+hl+lh; NT=1: hh only.
// Tile BMTx128, BK=32, global_load_lds staging, LDS swizzle. Bigger BMT =
// fewer x-block-rows = less B re-fetch through per-XCD L2 (measured lever:
// r16 -77us, r17 -335us; r18 BMT=256 cut FETCH 600->385MB but 98KB dbuf LDS
// -> 1 blk/CU regressed). So BMT=256 runs SINGLE-buffered (48KB -> 3 blk/CU;
// r14 measured counted-vmcnt dbuf as neutral vs the __syncthreads drain loop,
// so nothing is lost). BMT<=128 keeps the r17 double-buffer path unchanged.
// Output modes: 1=f32 C1; 3=bf16 hi/lo planes; 4=planes transposed;
// 5=QKV routing; 6=dual f32 seg->C1|C3.
template<int BMT, int NT, bool EXPERT, bool GATHER, int OM>
__launch_bounds__(256, (NT == 3 ? (BMT == 256 ? 3 : BMT == 128 ? 2 : 3)
                                : 4))
__global__ void k_gemmp(const bf16* __restrict__ Ah, const bf16* __restrict__ Al,
                        const bf16* __restrict__ Bh, const bf16* __restrict__ Bl,
                        void* __restrict__ C1, void* __restrict__ C2,
                        void* __restrict__ C3, void* __restrict__ C4,
                        void* __restrict__ C5, void* __restrict__ C6,
                        int M, int N, int Kd, int lda, int ldc,
                        const int* __restrict__ perm, const int* __restrict__ cnt,
                        const int* __restrict__ ofs)
{
  constexpr int PL = (NT == 3) ? 2 : 1;
  constexpr int NBUF = (BMT == 256) ? 1 : 2;
  constexpr int ASUB = BMT / 16;        // A 16-row subtiles per plane
  constexpr int AISS = PL * ASUB;
  constexpr int BISS = PL * 8;
  constexpr int QPW = (AISS + BISS) / 4;
  constexpr int IF = BMT / 32;

  const int bx = (int)blockIdx.x;
  const int by = (int)blockIdx.y;

  int m_count = M, row_base = 0;
  size_t boff = 0;
  if (EXPERT) {
    int e = blockIdx.z;
    m_count = cnt[e];
    if (bx * BMT >= m_count) return;
    row_base = ofs[e];
    boff = (size_t)e * (size_t)N * (size_t)Kd;
  }
  const int tid = threadIdx.x, lane = tid & 63, wid = tid >> 6;
  const int wm = (wid >> 1) * (BMT / 2), wn = (wid & 1) * 64;
  const int lr = lane & 15, g = lane >> 4;
  const int n0 = by * 128;
  const int m0 = bx * BMT;

  __shared__ bf16 As[NBUF][PL][BMT][32];
  __shared__ bf16 Bs[NBUF][PL][128][32];

  const bf16* srcp[QPW];
#pragma unroll
  for (int j = 0; j < QPW; ++j) {
    int q = wid * QPW + j;
    int r16 = lane >> 2;
    int kc = (lane & 3) ^ ((lane >> 3) & 3);   // source pre-swizzle
    if (q < AISS) {
      int pl = q / ASUB, sub = q % ASUB;
      int r = sub * 16 + r16;
      int tok;
      if (EXPERT) {
        int lrow = m0 + r;
        if (lrow >= m_count) lrow = m_count - 1;
        tok = GATHER ? perm[row_base + lrow] : (row_base + lrow);
      } else {
        tok = m0 + r;
      }
      const bf16* base = (pl == 0) ? Ah : Al;
      srcp[j] = base + (size_t)tok * lda + kc * 8;
    } else {
      int qb = q - AISS;
      int pl = qb >> 3, sub = qb & 7;
      int nrow = sub * 16 + r16;
      const bf16* base = (pl == 0) ? Bh : Bl;
      srcp[j] = base + boff + (size_t)(n0 + nrow) * Kd + kc * 8;
    }
  }

  f32x4 acc[IF][4];
#pragma unroll
  for (int i = 0; i < IF; ++i)
#pragma unroll
    for (int j = 0; j < 4; ++j)
      acc[i][j] = (f32x4){0.f, 0.f, 0.f, 0.f};

  auto ISSUE = [&](int buf, int k0) {
#pragma unroll
    for (int j = 0; j < QPW; ++j) {
      int q = wid * QPW + j;
      bf16* dst;
      if (q < AISS) {
        int pl = q / ASUB, sub = q % ASUB;
        dst = &As[buf][pl][sub * 16][0];
      } else {
        int qb = q - AISS;
        int pl = qb >> 3, sub = qb & 7;
        dst = &Bs[buf][pl][sub * 16][0];
      }
      gload16(srcp[j] + k0, dst);
    }
  };

  const int gs = (g ^ ((lr >> 1) & 3)) * 8;    // swizzled read slot
  const int NTk = Kd >> 5;                     // >= 44 for all callers
  ISSUE(0, 0);
  if (NBUF == 2) ISSUE(1, 32);
  for (int t = 0; t < NTk; ++t) {
    const int cb = (NBUF == 2) ? (t & 1) : 0;
    if constexpr (NBUF == 2) {
      if (t + 1 < NTk) {
        asm volatile("s_waitcnt vmcnt(%0)" :: "n"(QPW) : "memory");
      } else {
        asm volatile("s_waitcnt vmcnt(0)" ::: "memory");
      }
      __builtin_amdgcn_sched_barrier(0);
      __builtin_amdgcn_s_barrier();            // tile t resident for all waves
      __builtin_amdgcn_sched_barrier(0);
    } else {
      __syncthreads();                         // drains vmcnt: tile t resident
    }
    bf16x8 bfr[4][PL], afr[IF][PL];
#pragma unroll
    for (int jj = 0; jj < 4; ++jj)
#pragma unroll
      for (int pl = 0; pl < PL; ++pl)
        bfr[jj][pl] = *(const bf16x8*)&Bs[cb][pl][wn + jj * 16 + lr][gs];
#pragma unroll
    for (int i = 0; i < IF; ++i)
#pragma unroll
      for (int pl = 0; pl < PL; ++pl)
        afr[i][pl] = *(const bf16x8*)&As[cb][pl][wm + i * 16 + lr][gs];
    if constexpr (NBUF == 2) {
      asm volatile("s_waitcnt lgkmcnt(0)" ::: "memory"); // my reads complete
      __builtin_amdgcn_sched_barrier(0);
      __builtin_amdgcn_s_barrier();            // all waves done reading buf cb
      __builtin_amdgcn_sched_barrier(0);
      if (t + 2 < NTk) ISSUE(cb, (t + 2) << 5);
    } else {
      __syncthreads();                         // all waves done reading buf 0
      if (t + 1 < NTk) ISSUE(0, (t + 1) << 5); // loads fly under MFMA
    }
#pragma unroll
    for (int i = 0; i < IF; ++i)
#pragma unroll
      for (int jj = 0; jj < 4; ++jj) {
        f32x4 a2 = acc[i][jj];
        a2 = __builtin_amdgcn_mfma_f32_16x16x32_bf16(afr[i][0], bfr[jj][0], a2, 0, 0, 0);
        if (NT == 3) {
          a2 = __builtin_amdgcn_mfma_f32_16x16x32_bf16(afr[i][0], bfr[jj][1], a2, 0, 0, 0);
          a2 = __builtin_amdgcn_mfma_f32_16x16x32_bf16(afr[i][1], bfr[jj][0], a2, 0, 0, 0);
        }
        acc[i][jj] = a2;
      }
  }

  // ---- output routing (block-uniform; 128 % ldc-segment == 0 everywhere) ----
  void *O1 = C1, *O2 = C2;
  bool otrans = (OM == 4);
  int coff = 0;
  if (OM == 5) {
    int seg = n0 / ldc;
    coff = seg * ldc;
    if (seg == 1)      { O1 = C3; O2 = C4; }
    else if (seg == 2) { O1 = C5; O2 = C6; otrans = true; }
  } else if (OM == 6) {
    int seg = n0 / ldc;
    coff = seg * ldc;
    if (seg) O1 = C3;
  }

  const int r0 = g * 4;
#pragma unroll
  for (int i = 0; i < IF; ++i) {
    int lrow0 = m0 + wm + i * 16 + r0;
#pragma unroll
    for (int j = 0; j < 4; ++j) {
      int col = n0 + wn + j * 16 + lr - coff;
      if (OM == 4 || (OM == 5 && otrans)) {
        bf16x4 ph, pl;
#pragma unroll
        for (int r = 0; r < 4; ++r) { bf16 hb, lb; split1(acc[i][j][r], hb, lb); ph[r] = hb; pl[r] = lb; }
        *(bf16x4*)&((bf16*)O1)[(size_t)col * ldc + lrow0] = ph;
        *(bf16x4*)&((bf16*)O2)[(size_t)col * ldc + lrow0] = pl;
      } else {
#pragma unroll
        for (int r = 0; r < 4; ++r) {
          int lrow = lrow0 + r;
          if (EXPERT && lrow >= m_count) continue;
          size_t off = (size_t)(row_base + lrow) * ldc + col;
          if (OM == 1 || OM == 6) {
            ((float*)O1)[off] = acc[i][j][r];
          } else {  // OM == 3 or OM == 5 row-major planes
            bf16 hb, lb; split1(acc[i][j][r], hb, lb);
            ((bf16*)O1)[off] = hb;
            ((bf16*)O2)[off] = lb;
          }
        }
      }
    }
  }
}

// ------------------------------------ split-precision flash attention -------
// grid (T/32, H); block = 4 waves; 32 q rows per block as two 16-row tiles A/B.
// Waves split the key range with private (m,l,O) per q-tile; K/V fragments
// loaded once per key-tile and reused for both q-tiles. Swapped QK^T.
__launch_bounds__(256)
__global__ void k_attns(const bf16* __restrict__ Qh, const bf16* __restrict__ Ql,
                        const bf16* __restrict__ Kh, const bf16* __restrict__ Kl,
                        const bf16* __restrict__ Vh, const bf16* __restrict__ Vl,
                        bf16* __restrict__ Oh, bf16* __restrict__ Ol)
{
  const int tid = threadIdx.x;
  const int lane = tid & 63, wid = tid >> 6;
  const int head = blockIdx.y;
  const int qbase = (gridDim.x - 1 - blockIdx.x) * 32;
  const int lr = lane & 15, g = lane >> 4;

  __shared__ float o_l[4][16][132];
  __shared__ float m_l[4][16], l_l[4][16];
  bf16* plbase = (bf16*)&o_l[0][0][0];
  bf16 (*pl_h)[40] = (bf16(*)[40])(plbase + wid * 16 * 40);
  bf16 (*pl_l)[40] = (bf16(*)[40])(plbase + (4 + wid) * 16 * 40);

  bf16x8 qfhA[4], qflA[4], qfhB[4], qflB[4];
  {
    size_t qoffA = (size_t)(qbase + lr) * DD + head * HDIM;
    size_t qoffB = qoffA + (size_t)16 * DD;
#pragma unroll
    for (int c = 0; c < 4; ++c) {
      qfhA[c] = *(const bf16x8*)(Qh + qoffA + c * 32 + g * 8);
      qflA[c] = *(const bf16x8*)(Ql + qoffA + c * 32 + g * 8);
      qfhB[c] = *(const bf16x8*)(Qh + qoffB + c * 32 + g * 8);
      qflB[c] = *(const bf16x8*)(Ql + qoffB + c * 32 + g * 8);
    }
  }

  f32x4 oA[8], oB[8];
#pragma unroll
  for (int d = 0; d < 8; ++d) {
    oA[d] = (f32x4){0.f, 0.f, 0.f, 0.f};
    oB[d] = (f32x4){0.f, 0.f, 0.f, 0.f};
  }
  float mA = -1e30f, lA = 0.f;
  float mB = -1e30f, lB = 0.f;

  const int qend = qbase + 32;
  for (int kb = wid * 32; kb < qend; kb += 128) {
    f32x4 sA0 = {0.f,0.f,0.f,0.f}, sA1 = {0.f,0.f,0.f,0.f};
    f32x4 sB0 = {0.f,0.f,0.f,0.f}, sB1 = {0.f,0.f,0.f,0.f};
    size_t k0off = (size_t)(kb + lr) * DD + head * HDIM;
    size_t k1off = k0off + (size_t)16 * DD;
#pragma unroll
    for (int c = 0; c < 4; ++c) {
      bf16x8 kh0 = *(const bf16x8*)(Kh + k0off + c * 32 + g * 8);
      bf16x8 kl0 = *(const bf16x8*)(Kl + k0off + c * 32 + g * 8);
      sA0 = __builtin_amdgcn_mfma_f32_16x16x32_bf16(kh0, qfhA[c], sA0, 0, 0, 0);
      sA0 = __builtin_amdgcn_mfma_f32_16x16x32_bf16(kl0, qfhA[c], sA0, 0, 0, 0);
      sA0 = __builtin_amdgcn_mfma_f32_16x16x32_bf16(kh0, qflA[c], sA0, 0, 0, 0);
      sB0 = __builtin_amdgcn_mfma_f32_16x16x32_bf16(kh0, qfhB[c], sB0, 0, 0, 0);
      sB0 = __builtin_amdgcn_mfma_f32_16x16x32_bf16(kl0, qfhB[c], sB0, 0, 0, 0);
      sB0 = __builtin_amdgcn_mfma_f32_16x16x32_bf16(kh0, qflB[c], sB0, 0, 0, 0);
      bf16x8 kh1 = *(const bf16x8*)(Kh + k1off + c * 32 + g * 8);
      bf16x8 kl1 = *(const bf16x8*)(Kl + k1off + c * 32 + g * 8);
      sA1 = __builtin_amdgcn_mfma_f32_16x16x32_bf16(kh1, qfhA[c], sA1, 0, 0, 0);
      sA1 = __builtin_amdgcn_mfma_f32_16x16x32_bf16(kl1, qfhA[c], sA1, 0, 0, 0);
      sA1 = __builtin_amdgcn_mfma_f32_16x16x32_bf16(kh1, qflA[c], sA1, 0, 0, 0);
      sB1 = __builtin_amdgcn_mfma_f32_16x16x32_bf16(kh1, qfhB[c], sB1, 0, 0, 0);
      sB1 = __builtin_amdgcn_mfma_f32_16x16x32_bf16(kl1, qfhB[c], sB1, 0, 0, 0);
      sB1 = __builtin_amdgcn_mfma_f32_16x16x32_bf16(kh1, qflB[c], sB1, 0, 0, 0);
    }
    float p0A[4], p1A[4];
    {
      float mloc = -1e30f;
      const int q = qbase + lr;
#pragma unroll
      for (int r = 0; r < 4; ++r) {
        int k0i = kb + g * 4 + r;
        float a0 = sA0[r] * 0.08838834764831845f;
        float a1 = sA1[r] * 0.08838834764831845f;
        if (k0i > q)      a0 = -1e30f;
        if (k0i + 16 > q) a1 = -1e30f;
        p0A[r] = a0; p1A[r] = a1;
        mloc = fmaxf(mloc, fmaxf(a0, a1));
      }
      mloc = fmaxf(mloc, __shfl_xor(mloc, 16, 64));
      mloc = fmaxf(mloc, __shfl_xor(mloc, 32, 64));
      float mn = fmaxf(mA, mloc);
      float alpha = __expf(mA - mn);
      mA = mn;
      float ps = 0.f;
#pragma unroll
      for (int r = 0; r < 4; ++r) {
        p0A[r] = __expf(p0A[r] - mn);
        p1A[r] = __expf(p1A[r] - mn);
        ps += p0A[r] + p1A[r];
      }
      ps += __shfl_xor(ps, 16, 64);
      ps += __shfl_xor(ps, 32, 64);
      lA = lA * alpha + ps;
      float alr[4];
#pragma unroll
      for (int r = 0; r < 4; ++r) alr[r] = __shfl(alpha, g * 4 + r, 64);
#pragma unroll
      for (int d = 0; d < 8; ++d)
#pragma unroll
        for (int r = 0; r < 4; ++r) oA[d][r] *= alr[r];
    }
    float p0B[4], p1B[4];
    {
      float mloc = -1e30f;
      const int q = qbase + 16 + lr;
#pragma unroll
      for (int r = 0; r < 4; ++r) {
        int k0i = kb + g * 4 + r;
        float a0 = sB0[r] * 0.08838834764831845f;
        float a1 = sB1[r] * 0.08838834764831845f;
        if (k0i > q)      a0 = -1e30f;
        if (k0i + 16 > q) a1 = -1e30f;
        p0B[r] = a0; p1B[r] = a1;
        mloc = fmaxf(mloc, fmaxf(a0, a1));
      }
      mloc = fmaxf(mloc, __shfl_xor(mloc, 16, 64));
      mloc = fmaxf(mloc, __shfl_xor(mloc, 32, 64));
      float mn = fmaxf(mB, mloc);
      float alpha = __expf(mB - mn);
      mB = mn;
      float ps = 0.f;
#pragma unroll
      for (int r = 0; r < 4; ++r) {
        p0B[r] = __expf(p0B[r] - mn);
        p1B[r] = __expf(p1B[r] - mn);
        ps += p0B[r] + p1B[r];
      }
      ps += __shfl_xor(ps, 16, 64);
      ps += __shfl_xor(ps, 32, 64);
      lB = lB * alpha + ps;
      float alr[4];
#pragma unroll
      for (int r = 0; r < 4; ++r) alr[r] = __shfl(alpha, g * 4 + r, 64);
#pragma unroll
      for (int d = 0; d < 8; ++d)
#pragma unroll
        for (int r = 0; r < 4; ++r) oB[d][r] *= alr[r];
    }
#pragma unroll
    for (int r = 0; r < 4; ++r) {
      bf16 hb, lb;
      split1(p0A[r], hb, lb);
      pl_h[lr][g * 4 + r] = hb;
      pl_l[lr][g * 4 + r] = lb;
      split1(p1A[r], hb, lb);
      pl_h[lr][16 + g * 4 + r] = hb;
      pl_l[lr][16 + g * 4 + r] = lb;
    }
    bf16x8 pahA = *(const bf16x8*)&pl_h[lr][g * 8];
    bf16x8 palA = *(const bf16x8*)&pl_l[lr][g * 8];
#pragma unroll
    for (int r = 0; r < 4; ++r) {
      bf16 hb, lb;
      split1(p0B[r], hb, lb);
      pl_h[lr][g * 4 + r] = hb;
      pl_l[lr][g * 4 + r] = lb;
      split1(p1B[r], hb, lb);
      pl_h[lr][16 + g * 4 + r] = hb;
      pl_l[lr][16 + g * 4 + r] = lb;
    }
    bf16x8 pahB = *(const bf16x8*)&pl_h[lr][g * 8];
    bf16x8 palB = *(const bf16x8*)&pl_l[lr][g * 8];
#pragma unroll
    for (int d = 0; d < 8; ++d) {
      size_t voff = (size_t)(head * HDIM + d * 16 + lr) * TT + kb + g * 8;
      bf16x8 vfh = *(const bf16x8*)(Vh + voff);
      bf16x8 vfl = *(const bf16x8*)(Vl + voff);
      oA[d] = __builtin_amdgcn_mfma_f32_16x16x32_bf16(pahA, vfh, oA[d], 0, 0, 0);
      oA[d] = __builtin_amdgcn_mfma_f32_16x16x32_bf16(pahA, vfl, oA[d], 0, 0, 0);
      oA[d] = __builtin_amdgcn_mfma_f32_16x16x32_bf16(palA, vfh, oA[d], 0, 0, 0);
      oB[d] = __builtin_amdgcn_mfma_f32_16x16x32_bf16(pahB, vfh, oB[d], 0, 0, 0);
      oB[d] = __builtin_amdgcn_mfma_f32_16x16x32_bf16(pahB, vfl, oB[d], 0, 0, 0);
      oB[d] = __builtin_amdgcn_mfma_f32_16x16x32_bf16(palB, vfh, oB[d], 0, 0, 0);
    }
  }

  __syncthreads();
  if (g == 0) {
    m_l[wid][lr] = mA;
    l_l[wid][lr] = lA;
  }
#pragma unroll
  for (int d = 0; d < 8; ++d)
#pragma unroll
    for (int r = 0; r < 4; ++r)
      o_l[wid][g * 4 + r][d * 16 + lr] = oA[d][r];
  __syncthreads();
  {
    const int row = tid >> 4;
    const int c0 = (tid & 15) * 8;
    float m0v = m_l[0][row], m1v = m_l[1][row], m2v = m_l[2][row], m3v = m_l[3][row];
    float ms = fmaxf(fmaxf(m0v, m1v), fmaxf(m2v, m3v));
    float s0v = __expf(m0v - ms), s1v = __expf(m1v - ms);
    float s2v = __expf(m2v - ms), s3v = __expf(m3v - ms);
    float lsum = l_l[0][row] * s0v + l_l[1][row] * s1v
               + l_l[2][row] * s2v + l_l[3][row] * s3v;
    float inv = 1.f / lsum;
    union { bf16 b[8]; uint4 u; } ph, pl;
#pragma unroll
    for (int j = 0; j < 8; ++j) {
      float v = o_l[0][row][c0 + j] * s0v + o_l[1][row][c0 + j] * s1v
              + o_l[2][row][c0 + j] * s2v + o_l[3][row][c0 + j] * s3v;
      bf16 hb, lb;
      split1(v * inv, hb, lb);
      ph.b[j] = hb; pl.b[j] = lb;
    }
    size_t oi = (size_t)(qbase + row) * DD + head * HDIM + c0;
    *(uint4*)(Oh + oi) = ph.u;
    *(uint4*)(Ol + oi) = pl.u;
  }
  __syncthreads();
  if (g == 0) {
    m_l[wid][lr] = mB;
    l_l[wid][lr] = lB;
  }
#pragma unroll
  for (int d = 0; d < 8; ++d)
#pragma unroll
    for (int r = 0; r < 4; ++r)
      o_l[wid][g * 4 + r][d * 16 + lr] = oB[d][r];
  __syncthreads();
  {
    const int row = tid >> 4;
    const int c0 = (tid & 15) * 8;
    float m0v = m_l[0][row], m1v = m_l[1][row], m2v = m_l[2][row], m3v = m_l[3][row];
    float ms = fmaxf(fmaxf(m0v, m1v), fmaxf(m2v, m3v));
    float s0v = __expf(m0v - ms), s1v = __expf(m1v - ms);
    float s2v = __expf(m2v - ms), s3v = __expf(m3v - ms);
    float lsum = l_l[0][row] * s0v + l_l[1][row] * s1v
               + l_l[2][row] * s2v + l_l[3][row] * s3v;
    float inv = 1.f / lsum;
    union { bf16 b[8]; uint4 u; } ph, pl;
#pragma unroll
    for (int j = 0; j < 8; ++j) {
      float v = o_l[0][row][c0 + j] * s0v + o_l[1][row][c0 + j] * s1v
              + o_l[2][row][c0 + j] * s2v + o_l[3][row][c0 + j] * s3v;
      bf16 hb, lb;
      split1(v * inv, hb, lb);
      ph.b[j] = hb; pl.b[j] = lb;
    }
    size_t oi = (size_t)(qbase + 16 + row) * DD + head * HDIM + c0;
    *(uint4*)(Oh + oi) = ph.u;
    *(uint4*)(Ol + oi) = pl.u;
  }
}

// ------------------------------------------------------------- helpers ------
__global__ void k_embed(const int* __restrict__ ids, const float* __restrict__ Em,
                        float* __restrict__ Hout)
{
  int t = blockIdx.x, tid = threadIdx.x;
  const float4* s = (const float4*)(Em + (size_t)ids[t] * DD);
  float4* dst = (float4*)(Hout + (size_t)t * DD);
  dst[tid] = s[tid];
  dst[tid + 256] = s[tid + 256];
}

template<bool ADDIN, bool WF32, bool FINAL>
__launch_bounds__(256)
__global__ void k_addrms(const float* __restrict__ Hin, float* __restrict__ Res,
                         const float* __restrict__ W,
                         bf16* __restrict__ Xh, bf16* __restrict__ Xl,
                         float* __restrict__ Xf)
{
  const int t = blockIdx.x, tid = threadIdx.x;
  const size_t base = (size_t)t * DD + tid * 8;
  float x[8];
  {
    const float4* hp = (const float4*)(Hin + base);
    float4 a = hp[0], b = hp[1];
    x[0]=a.x; x[1]=a.y; x[2]=a.z; x[3]=a.w;
    x[4]=b.x; x[5]=b.y; x[6]=b.z; x[7]=b.w;
    if (ADDIN) {
      const float4* rp = (const float4*)(Res + base);
      float4 c = rp[0], d = rp[1];
      x[0]+=c.x; x[1]+=c.y; x[2]+=c.z; x[3]+=c.w;
      x[4]+=d.x; x[5]+=d.y; x[6]+=d.z; x[7]+=d.w;
    }
  }
  {
    float4* rp = (float4*)(Res + base);
    rp[0] = make_float4(x[0], x[1], x[2], x[3]);
    rp[1] = make_float4(x[4], x[5], x[6], x[7]);
  }
  float ss = 0.f;
#pragma unroll
  for (int j = 0; j < 8; ++j) ss += x[j] * x[j];
#pragma unroll
  for (int off = 32; off; off >>= 1) ss += __shfl_xor(ss, off, 64);
  __shared__ float red[4];
  if ((tid & 63) == 0) red[tid >> 6] = ss;
  __syncthreads();
  float tot = red[0] + red[1] + red[2] + red[3];
  float sc = rsqrtf(tot * (1.0f / DD) + 1e-6f);
  float y[8];
#pragma unroll
  for (int j = 0; j < 8; ++j) y[j] = x[j] * sc * W[tid * 8 + j];
  if (!FINAL) {
    union { bf16 b[8]; uint4 u; } ph, pl;
#pragma unroll
    for (int j = 0; j < 8; ++j) { bf16 hb, lb; split1(y[j], hb, lb); ph.b[j] = hb; pl.b[j] = lb; }
    *(uint4*)(Xh + base) = ph.u;
    *(uint4*)(Xl + base) = pl.u;
  }
  if (WF32 || FINAL) {
    float4* xp = (float4*)(Xf + base);
    xp[0] = make_float4(y[0], y[1], y[2], y[3]);
    xp[1] = make_float4(y[4], y[5], y[6], y[7]);
  }
}

__global__ void k_rope2(bf16* __restrict__ Qh, bf16* __restrict__ Ql,
                        bf16* __restrict__ Kh, bf16* __restrict__ Kl,
                        const int* __restrict__ pos)
{
  int idx = blockIdx.x * 256 + threadIdx.x;
  int d = idx & 63;
  int h = (idx >> 6) & (HH - 1);
  int t = idx >> 10;
  if (t >= TT) return;
  double inv = pow(1.0e6, -(double)d / 64.0);
  double ang = (double)pos[t] * inv;
  double sd, cd;
  sincos(ang, &sd, &cd);
  float sn = (float)sd, cs = (float)cd;
  size_t base = (size_t)t * DD + h * HDIM + d;
  float q1 = (float)Qh[base] + (float)Ql[base];
  float q2 = (float)Qh[base + 64] + (float)Ql[base + 64];
  float qa = q1 * cs - q2 * sn, qb = q1 * sn + q2 * cs;
  bf16 hb, lb;
  split1(qa, hb, lb); Qh[base] = hb;      Ql[base] = lb;
  split1(qb, hb, lb); Qh[base + 64] = hb; Ql[base + 64] = lb;
  float k1 = (float)Kh[base] + (float)Kl[base];
  float k2 = (float)Kh[base + 64] + (float)Kl[base + 64];
  float ka = k1 * cs - k2 * sn, kb2 = k1 * sn + k2 * cs;
  split1(ka, hb, lb);  Kh[base] = hb;      Kl[base] = lb;
  split1(kb2, hb, lb); Kh[base + 64] = hb; Kl[base + 64] = lb;
}

__launch_bounds__(64)
__global__ void k_router(const float* __restrict__ Xf, const float* __restrict__ RW,
                         const float* __restrict__ SGW, int* __restrict__ eidx,
                         float* __restrict__ ew, float* __restrict__ sgate,
                         int* __restrict__ cnt)
{
  const int t = blockIdx.x, lane = threadIdx.x;
  const float* x = Xf + (size_t)t * DD;
  float acc[8] = {0,0,0,0,0,0,0,0};
  float sg = 0.f;
  for (int i = lane; i < DD; i += 64) {
    float xv = x[i];
    const float4* w = (const float4*)(RW + (size_t)i * NE);
    float4 w0 = w[0], w1 = w[1];
    acc[0] += xv * w0.x; acc[1] += xv * w0.y; acc[2] += xv * w0.z; acc[3] += xv * w0.w;
    acc[4] += xv * w1.x; acc[5] += xv * w1.y; acc[6] += xv * w1.z; acc[7] += xv * w1.w;
    sg += xv * SGW[i];
  }
#pragma unroll
  for (int off = 32; off; off >>= 1) {
#pragma unroll
    for (int e = 0; e < 8; ++e) acc[e] += __shfl_xor(acc[e], off, 64);
    sg += __shfl_xor(sg, off, 64);
  }
  if (lane == 0) {
    int i0 = 0; float v0 = acc[0];
    for (int e = 1; e < 8; ++e) if (acc[e] > v0) { v0 = acc[e]; i0 = e; }
    int i1 = -1; float v1 = -1e30f;
    for (int e = 0; e < 8; ++e) if (e != i0 && acc[e] > v1) { v1 = acc[e]; i1 = e; }
    float w0 = 1.f / (1.f + expf(v1 - v0));
    eidx[2*t] = i0; eidx[2*t+1] = i1;
    ew[2*t] = w0; ew[2*t+1] = 1.f - w0;
    sgate[t] = 1.f / (1.f + expf(-sg));
    atomicAdd(&cnt[i0], 1);
    atomicAdd(&cnt[i1], 1);
  }
}

__global__ void k_scan(const int* __restrict__ cnt, int* __restrict__ ofs)
{
  if (threadIdx.x == 0) {
    int s = 0;
    for (int e = 0; e < NE; ++e) { ofs[e] = s; s += cnt[e]; }
    ofs[NE] = s;
  }
}

__global__ void k_assign(const int* __restrict__ eidx, const int* __restrict__ ofs,
                         int* __restrict__ cursor, int* __restrict__ perm,
                         int* __restrict__ posof)
{
  int t = blockIdx.x * 256 + threadIdx.x;
  if (t >= TT) return;
#pragma unroll
  for (int j = 0; j < 2; ++j) {
    int e = eidx[2*t + j];
    int p = ofs[e] + atomicAdd(&cursor[e], 1);
    perm[p] = t;
    posof[2*t + j] = p;
  }
}

// silu(g)*u from f32 inputs -> bf16 hi/lo planes
__global__ void k_silup(const float* __restrict__ G, const float* __restrict__ U,
                        bf16* __restrict__ H, bf16* __restrict__ L)
{
  int i = (blockIdx.x * 256 + threadIdx.x) * 4;
  float4 g = *(const float4*)(G + i);
  float4 u = *(const float4*)(U + i);
  float s[4];
  s[0] = g.x / (1.f + expf(-g.x)) * u.x;
  s[1] = g.y / (1.f + expf(-g.y)) * u.y;
  s[2] = g.z / (1.f + expf(-g.z)) * u.z;
  s[3] = g.w / (1.f + expf(-g.w)) * u.w;
  bf16x4 h, l;
#pragma unroll
  for (int j = 0; j < 4; ++j) { bf16 hb, lb; split1(s[j], hb, lb); h[j] = hb; l[j] = lb; }
  *(bf16x4*)(H + i) = h;
  *(bf16x4*)(L + i) = l;
}

__global__ void k_combine(const float* __restrict__ Y, const float* __restrict__ SH,
                          const float* __restrict__ sgate, const float* __restrict__ ew,
                          const int* __restrict__ posof, float* __restrict__ Hout)
{
  int t = blockIdx.x, tid = threadIdx.x;
  int p0 = posof[2*t], p1 = posof[2*t+1];
  float w0 = ew[2*t], w1 = ew[2*t+1];
  float sgv = sgate[t];
  int d0 = tid * 8;
  const float4* a = (const float4*)(Y + (size_t)p0 * DD + d0);
  const float4* b = (const float4*)(Y + (size_t)p1 * DD + d0);
  float4 a0 = a[0], a1 = a[1], b0 = b[0], b1 = b[1];
  float y0[8] = {a0.x,a0.y,a0.z,a0.w,a1.x,a1.y,a1.z,a1.w};
  float y1[8] = {b0.x,b0.y,b0.z,b0.w,b1.x,b1.y,b1.z,b1.w};
  const float4* shp = (const float4*)(SH + (size_t)t * DD + d0);
  float4 sa = shp[0], sb = shp[1];
  float shv[8] = {sa.x, sa.y, sa.z, sa.w, sb.x, sb.y, sb.z, sb.w};
  float out[8];
#pragma unroll
  for (int j = 0; j < 8; ++j)
    out[j] = (y0[j] * w0 + y1[j] * w1 + sgv * shv[j]) * 0.70710678118654752f;
  float4* op = (float4*)(Hout + (size_t)t * DD + d0);
  op[0] = make_float4(out[0], out[1], out[2], out[3]);
  op[1] = make_float4(out[4], out[5], out[6], out[7]);
}

// -------------------------------------------------------------- driver ------
extern "C" void kernel_launch(void* const* d_in, const int* in_sizes, int n_in,
                              void* d_out, int out_size, void* d_ws, size_t ws_size,
                              hipStream_t stream)
{
  (void)in_sizes; (void)n_in; (void)out_size; (void)ws_size;
  const int*   ids  = (const int*)d_in[0];
  const int*   pos  = (const int*)d_in[1];
  const float* emb  = (const float*)d_in[2];
  const float* qw   = (const float*)d_in[3];
  const float* kw   = (const float*)d_in[4];
  const float* vw   = (const float*)d_in[5];
  const float* ow   = (const float*)d_in[6];
  const float* ln1  = (const float*)d_in[7];
  const float* ln2  = (const float*)d_in[8];
  const float* rw   = (const float*)d_in[9];
  const float* sgw  = (const float*)d_in[10];
  const float* wg   = (const float*)d_in[11];
  const float* wu   = (const float*)d_in[12];
  const float* wd   = (const float*)d_in[13];
  const float* swg  = (const float*)d_in[14];
  const float* swu  = (const float*)d_in[15];
  const float* swd  = (const float*)d_in[16];
  const float* fln  = (const float*)d_in[17];

  char* p = (char*)d_ws;
  auto alloc = [&](size_t b) { char* r = p; p += (b + 255) & ~(size_t)255; return r; };

  const size_t TD = (size_t)TT * DD;
  float* resid = (float*)alloc(TD * 4);
  float* hbuf  = (float*)alloc(TD * 4);
  float* xf    = (float*)alloc(TD * 4);
  bf16*  xh    = (bf16*) alloc(TD * 2);
  bf16*  xl    = (bf16*) alloc(TD * 2);
  bf16*  qhb   = (bf16*) alloc(TD * 2);
  bf16*  qlb   = (bf16*) alloc(TD * 2);
  bf16*  khb   = (bf16*) alloc(TD * 2);
  bf16*  klb   = (bf16*) alloc(TD * 2);
  bf16*  vth   = (bf16*) alloc(TD * 2);
  bf16*  vtl   = (bf16*) alloc(TD * 2);
  bf16*  aoh   = (bf16*) alloc(TD * 2);
  bf16*  aol   = (bf16*) alloc(TD * 2);
  float* shb   = (float*)alloc(TD * 4);
  const size_t SGF = (size_t)TT * FSS;
  const size_t GEF = (size_t)TT * TOPK * FF;
  bf16*  shph  = (bf16*) alloc(SGF * 2);
  bf16*  shpl  = (bf16*) alloc(SGF * 2);
  bf16*  geph  = (bf16*) alloc(GEF * 2);
  bf16*  gepl  = (bf16*) alloc(GEF * 2);
  float* region = (float*)alloc(2 * SGF * 4);
  float* sgbf = region;
  float* subf = region + SGF;
  float* gebf = region;
  float* uebf = region + GEF;
  float* ybf  = region + 2 * GEF;
  const size_t WME = (size_t)NE * DD * FF;
  bf16* wbh = (bf16*)alloc(WME * 2);
  bf16* wbl = (bf16*)alloc(WME * 2);
  int*   eidx  = (int*)  alloc((size_t)TT * TOPK * 4);
  float* ewb   = (float*)alloc((size_t)TT * TOPK * 4);
  float* sgate = (float*)alloc((size_t)TT * 4);
  int*   perm  = (int*)  alloc((size_t)TT * TOPK * 4);
  int*   posof = (int*)  alloc((size_t)TT * TOPK * 4);
  int*   cnt   = (int*)  alloc(64);
  int*   ofs   = (int*)  alloc(64);
  int*   cursor = cnt + 8;

  k_embed<<<TT, 256, 0, stream>>>(ids, emb, hbuf);

  for (int l = 0; l < NL; ++l) {
    const float* qw_l  = qw  + (size_t)l * DD * DD;
    const float* kw_l  = kw  + (size_t)l * DD * DD;
    const float* vw_l  = vw  + (size_t)l * DD * DD;
    const float* ow_l  = ow  + (size_t)l * DD * DD;
    const float* ln1_l = ln1 + (size_t)l * DD;
    const float* ln2_l = ln2 + (size_t)l * DD;
    const float* rw_l  = rw  + (size_t)l * DD * NE;
    const float* sgw_l = sgw + (size_t)l * DD;
    const float* wg_l  = wg  + (size_t)l * NE * DD * FF;
    const float* wu_l  = wu  + (size_t)l * NE * DD * FF;
    const float* wd_l  = wd  + (size_t)l * NE * FF * DD;
    const float* swg_l = swg + (size_t)l * DD * FSS;
    const float* swu_l = swu + (size_t)l * DD * FSS;
    const float* swd_l = swd + (size_t)l * FSS * DD;
    const bool last = (l == NL - 1);

    if (l == 0)
      k_addrms<false,false,false><<<TT,256,0,stream>>>(hbuf, resid, ln1_l, xh, xl, nullptr);
    else
      k_addrms<true, false,false><<<TT,256,0,stream>>>(hbuf, resid, ln1_l, xh, xl, nullptr);

    // ---- attention: fused QKV (BMT=256, single-buffer), rope/attn/O ----
    k_wtrans<true><<<dim3(32,32),256,0,stream>>>(qw_l, wbh, wbl, DD, DD, 0,    3*DD);
    k_wtrans<true><<<dim3(32,32),256,0,stream>>>(kw_l, wbh, wbl, DD, DD, DD,   3*DD);
    k_wtrans<true><<<dim3(32,32),256,0,stream>>>(vw_l, wbh, wbl, DD, DD, 2*DD, 3*DD);
    k_gemmp<256,3,false,false,5><<<dim3(8,48),256,0,stream>>>(xh, xl, wbh, wbl,
        qhb, qlb, khb, klb, vth, vtl, TT, 3*DD, DD, DD, DD, nullptr,nullptr,nullptr);
    k_rope2<<<(TT*HH*64)/256, 256, 0, stream>>>(qhb, qlb, khb, klb, pos);
    k_attns<<<dim3(TT/32, HH), 256, 0, stream>>>(qhb, qlb, khb, klb, vth, vtl, aoh, aol);
    k_wtrans<true><<<dim3(32,32),256,0,stream>>>(ow_l, wbh, wbl, DD, DD, 0, DD);
    k_gemmp<128,3,false,false,1><<<dim3(16,16),256,0,stream>>>(aoh, aol, wbh, wbl,
        hbuf, nullptr, nullptr, nullptr, nullptr, nullptr, TT, DD, DD, DD, DD, nullptr,nullptr,nullptr);

    k_addrms<true,true,false><<<TT,256,0,stream>>>(hbuf, resid, ln2_l, xh, xl, xf);

    hipMemsetAsync(cnt, 0, 64, stream);
    k_router<<<TT, 64, 0, stream>>>(xf, rw_l, sgw_l, eidx, ewb, sgate, cnt);
    k_scan<<<1, 64, 0, stream>>>(cnt, ofs);
    k_assign<<<TT/256, 256, 0, stream>>>(eidx, ofs, cursor, perm, posof);

    // ---- shared expert: fused swg+swu (BMT=256, single-buffer), silu, swd --
    if (!last) {
      k_wtrans<true><<<dim3(32,88),256,0,stream>>>(swg_l, wbh, wbl, DD, FSS, 0,   2*FSS);
      k_wtrans<true><<<dim3(32,88),256,0,stream>>>(swu_l, wbh, wbl, DD, FSS, FSS, 2*FSS);
      k_gemmp<256,3,false,false,6><<<dim3(8,88),256,0,stream>>>(xh, xl, wbh, wbl,
          sgbf, nullptr, subf, nullptr, nullptr, nullptr, TT, 2*FSS, DD, DD, FSS, nullptr,nullptr,nullptr);
      k_silup<<<(TT*FSS/4)/256, 256, 0, stream>>>(sgbf, subf, shph, shpl);
      k_wtrans<true><<<dim3(88,32),256,0,stream>>>(swd_l, wbh, wbl, FSS, DD, 0, DD);
      k_gemmp<128,3,false,false,1><<<dim3(16,16),256,0,stream>>>(shph, shpl, wbh, wbl,
          shb, nullptr, nullptr, nullptr, nullptr, nullptr, TT, DD, FSS, FSS, DD, nullptr,nullptr,nullptr);
    } else {
      k_wtrans<false><<<dim3(32,88),256,0,stream>>>(swg_l, wbh, wbl, DD, FSS, 0,   2*FSS);
      k_wtrans<false><<<dim3(32,88),256,0,stream>>>(swu_l, wbh, wbl, DD, FSS, FSS, 2*FSS);
      k_gemmp<256,1,false,false,6><<<dim3(8,88),256,0,stream>>>(xh, xl, wbh, wbl,
          sgbf, nullptr, subf, nullptr, nullptr, nullptr, TT, 2*FSS, DD, DD, FSS, nullptr,nullptr,nullptr);
      k_silup<<<(TT*FSS/4)/256, 256, 0, stream>>>(sgbf, subf, shph, shpl);
      k_wtrans<false><<<dim3(88,32),256,0,stream>>>(swd_l, wbh, wbl, FSS, DD, 0, DD);
      k_gemmp<128,1,false,false,1><<<dim3(16,16),256,0,stream>>>(shph, shpl, wbh, wbl,
          shb, nullptr, nullptr, nullptr, nullptr, nullptr, TT, DD, FSS, FSS, DD, nullptr,nullptr,nullptr);
    }

    // ---- routed experts (BMT=128, r17-winning config; natural block ids) ----
    if (!last) {
      k_wtrans<true><<<dim3(32,22,NE),256,0,stream>>>(wg_l, wbh, wbl, DD, FF, 0, FF);
      k_gemmp<128,3,true,true,1><<<dim3(16,11,NE),256,0,stream>>>(xh, xl, wbh, wbl,
          gebf, nullptr, nullptr, nullptr, nullptr, nullptr, TT, FF, DD, DD, FF, perm, cnt, ofs);
      k_wtrans<true><<<dim3(32,22,NE),256,0,stream>>>(wu_l, wbh, wbl, DD, FF, 0, FF);
      k_gemmp<128,3,true,true,1><<<dim3(16,11,NE),256,0,stream>>>(xh, xl, wbh, wbl,
          uebf, nullptr, nullptr, nullptr, nullptr, nullptr, TT, FF, DD, DD, FF, perm, cnt, ofs);
      k_silup<<<(GEF/4)/256, 256, 0, stream>>>(gebf, uebf, geph, gepl);
      k_wtrans<true><<<dim3(22,32,NE),256,0,stream>>>(wd_l, wbh, wbl, FF, DD, 0, DD);
      k_gemmp<128,3,true,false,1><<<dim3(16,16,NE),256,0,stream>>>(geph, gepl, wbh, wbl,
          ybf, nullptr, nullptr, nullptr, nullptr, nullptr, TT, DD, FF, FF, DD, nullptr, cnt, ofs);
    } else {
      k_wtrans<false><<<dim3(32,22,NE),256,0,stream>>>(wg_l, wbh, wbl, DD, FF, 0, FF);
      k_gemmp<128,1,true,true,1><<<dim3(16,11,NE),256,0,stream>>>(xh, xl, wbh, wbl,
          gebf, nullptr, nullptr, nullptr, nullptr, nullptr, TT, FF, DD, DD, FF, perm, cnt, ofs);
      k_wtrans<false><<<dim3(32,22,NE),256,0,stream>>>(wu_l, wbh, wbl, DD, FF, 0, FF);
      k_gemmp<128,1,true,true,1><<<dim3(16,11,NE),256,0,stream>>>(xh, xl, wbh, wbl,
          uebf, nullptr, nullptr, nullptr, nullptr, nullptr, TT, FF, DD, DD, FF, perm, cnt, ofs);
      k_silup<<<(GEF/4)/256, 256, 0, stream>>>(gebf, uebf, geph, gepl);
      k_wtrans<false><<<dim3(22,32,NE),256,0,stream>>>(wd_l, wbh, wbl, FF, DD, 0, DD);
      k_gemmp<128,1,true,false,1><<<dim3(16,16,NE),256,0,stream>>>(geph, gepl, wbh, wbl,
          ybf, nullptr, nullptr, nullptr, nullptr, nullptr, TT, DD, FF, FF, DD, nullptr, cnt, ofs);
    }
    k_combine<<<TT, 256, 0, stream>>>(ybf, shb, sgate, ewb, posof, hbuf);
  }

  k_addrms<true,false,true><<<TT,256,0,stream>>>(hbuf, resid, fln, nullptr, nullptr, (float*)d_out);
}

// Round 20
// 3213.833 us; speedup vs baseline: 2.6388x; 2.6388x over previous
//
#include <hip/hip_runtime.h>
#include <stdint.h>

#define TT 2048
#define DD 2048
#define HH 16
#define HDIM 128
#define NE 8
#define TOPK 2
#define FF 1408
#define FSS 5632
#define NL 2

typedef __bf16 bf16;
typedef __bf16 bf16x2 __attribute__((ext_vector_type(2)));
typedef __bf16 bf16x4 __attribute__((ext_vector_type(4)));
typedef __bf16 bf16x8 __attribute__((ext_vector_type(8)));
typedef float f32x4 __attribute__((ext_vector_type(4)));

__device__ __forceinline__ void split1(float f, bf16& h, bf16& l) {
  bf16 hb = (bf16)f;
  h = hb;
  l = (bf16)(f - (float)hb);
}

__device__ __forceinline__ void gload16(const void* g, void* l) {
  __builtin_amdgcn_global_load_lds((const __attribute__((address_space(1))) void*)g,
                                   (__attribute__((address_space(3))) void*)l, 16, 0, 0);
}

// ------------------------------------------------ weight transpose+convert --
// W f32 [Kd][N] (N contiguous) -> planes bf16 [Ntot][Kd] at column offset nofs.
template<bool LO>
__launch_bounds__(256)
__global__ void k_wtrans(const float* __restrict__ W, bf16* __restrict__ Wh,
                         bf16* __restrict__ Wl, int Kd, int N, int nofs, int Ntot)
{
  __shared__ float T[64][68];
  const size_t slabIn  = (size_t)blockIdx.z * (size_t)Kd * (size_t)N;
  const size_t slabOut = (size_t)blockIdx.z * (size_t)Kd * (size_t)Ntot;
  const float* Wp = W + slabIn;
  const int k0 = blockIdx.x * 64, n0 = blockIdx.y * 64;
  const int tid = threadIdx.x;
  const int rr = tid >> 2, c4 = (tid & 3) * 4;
  const float* src = Wp + (size_t)(k0 + rr) * N + n0 + c4;
#pragma unroll
  for (int j = 0; j < 4; ++j) {
    f32x4 v = *(const f32x4*)(src + j * 16);
    *(f32x4*)&T[rr][c4 + j * 16] = v;
  }
  __syncthreads();
  const int nn = tid >> 2, kk = (tid & 3) * 16;
  bf16x8 h0, h1, l0, l1;
#pragma unroll
  for (int j = 0; j < 8; ++j) {
    bf16 hb, lb;
    split1(T[kk + j][nn], hb, lb);
    h0[j] = hb; l0[j] = lb;
    split1(T[kk + 8 + j][nn], hb, lb);
    h1[j] = hb; l1[j] = lb;
  }
  size_t out = slabOut + (size_t)(nofs + n0 + nn) * Kd + k0 + kk;
  *(bf16x8*)&Wh[out] = h0;
  *(bf16x8*)&Wh[out + 8] = h1;
  if (LO) {
    *(bf16x8*)&Wl[out] = l0;
    *(bf16x8*)&Wl[out + 8] = l1;
  }
}

// ----------------------------------------------------- planar bf16 GEMM -----
// C[M,N] = (Ah+Al)[M,K] @ (Bh+Bl)[N,K]^T, NT=3: hh+hl+lh; NT=1: hh only.
// Tile BMTx128, BK=32, double-buffered global_load_lds staging with counted
// vmcnt across raw s_barriers. LDS swizzle. BMT=128 everywhere (dense AND
// expert): halving the number of x-block-rows halves B re-fetch through the
// per-XCD L2 (the one lever measured effective: r16 -77us, r17 -335us).
// BMT=256 is falsified: dbuf 98KB LDS -> 1 blk/CU regressed (r18); single-buf
// with min-waves=3 -> VGPR spill catastrophe (r19, VGPR=84, 10.5GB scratch
// traffic/dispatch). Expert kernels keep natural block ids (r12).
// Output modes: 1=f32 C1; 3=bf16 hi/lo planes; 4=planes transposed;
// 5=QKV routing; 6=dual f32 seg->C1|C3.
template<int BMT, int NT, bool EXPERT, bool GATHER, int OM>
__launch_bounds__(256, (NT == 3 ? (BMT == 128 ? 2 : 3) : 4))
__global__ void k_gemmp(const bf16* __restrict__ Ah, const bf16* __restrict__ Al,
                        const bf16* __restrict__ Bh, const bf16* __restrict__ Bl,
                        void* __restrict__ C1, void* __restrict__ C2,
                        void* __restrict__ C3, void* __restrict__ C4,
                        void* __restrict__ C5, void* __restrict__ C6,
                        int M, int N, int Kd, int lda, int ldc,
                        const int* __restrict__ perm, const int* __restrict__ cnt,
                        const int* __restrict__ ofs)
{
  constexpr int PL = (NT == 3) ? 2 : 1;
  constexpr int ASUB = BMT / 16;        // A 16-row subtiles per plane
  constexpr int AISS = PL * ASUB;
  constexpr int BISS = PL * 8;
  constexpr int QPW = (AISS + BISS) / 4;
  constexpr int IF = BMT / 32;

  const int bx = (int)blockIdx.x;
  const int by = (int)blockIdx.y;

  int m_count = M, row_base = 0;
  size_t boff = 0;
  if (EXPERT) {
    int e = blockIdx.z;
    m_count = cnt[e];
    if (bx * BMT >= m_count) return;
    row_base = ofs[e];
    boff = (size_t)e * (size_t)N * (size_t)Kd;
  }
  const int tid = threadIdx.x, lane = tid & 63, wid = tid >> 6;
  const int wm = (wid >> 1) * (BMT / 2), wn = (wid & 1) * 64;
  const int lr = lane & 15, g = lane >> 4;
  const int n0 = by * 128;
  const int m0 = bx * BMT;

  __shared__ bf16 As[2][PL][BMT][32];
  __shared__ bf16 Bs[2][PL][128][32];

  const bf16* srcp[QPW];
#pragma unroll
  for (int j = 0; j < QPW; ++j) {
    int q = wid * QPW + j;
    int r16 = lane >> 2;
    int kc = (lane & 3) ^ ((lane >> 3) & 3);   // source pre-swizzle
    if (q < AISS) {
      int pl = q / ASUB, sub = q % ASUB;
      int r = sub * 16 + r16;
      int tok;
      if (EXPERT) {
        int lrow = m0 + r;
        if (lrow >= m_count) lrow = m_count - 1;
        tok = GATHER ? perm[row_base + lrow] : (row_base + lrow);
      } else {
        tok = m0 + r;
      }
      const bf16* base = (pl == 0) ? Ah : Al;
      srcp[j] = base + (size_t)tok * lda + kc * 8;
    } else {
      int qb = q - AISS;
      int pl = qb >> 3, sub = qb & 7;
      int nrow = sub * 16 + r16;
      const bf16* base = (pl == 0) ? Bh : Bl;
      srcp[j] = base + boff + (size_t)(n0 + nrow) * Kd + kc * 8;
    }
  }

  f32x4 acc[IF][4];
#pragma unroll
  for (int i = 0; i < IF; ++i)
#pragma unroll
    for (int j = 0; j < 4; ++j)
      acc[i][j] = (f32x4){0.f, 0.f, 0.f, 0.f};

  auto ISSUE = [&](int buf, int k0) {
#pragma unroll
    for (int j = 0; j < QPW; ++j) {
      int q = wid * QPW + j;
      bf16* dst;
      if (q < AISS) {
        int pl = q / ASUB, sub = q % ASUB;
        dst = &As[buf][pl][sub * 16][0];
      } else {
        int qb = q - AISS;
        int pl = qb >> 3, sub = qb & 7;
        dst = &Bs[buf][pl][sub * 16][0];
      }
      gload16(srcp[j] + k0, dst);
    }
  };

  const int gs = (g ^ ((lr >> 1) & 3)) * 8;    // swizzled read slot
  const int NTk = Kd >> 5;                     // >= 44 for all callers
  ISSUE(0, 0);
  ISSUE(1, 32);
  for (int t = 0; t < NTk; ++t) {
    const int cb = t & 1;
    if (t + 1 < NTk) {
      asm volatile("s_waitcnt vmcnt(%0)" :: "n"(QPW) : "memory");
    } else {
      asm volatile("s_waitcnt vmcnt(0)" ::: "memory");
    }
    __builtin_amdgcn_sched_barrier(0);
    __builtin_amdgcn_s_barrier();              // tile t resident for all waves
    __builtin_amdgcn_sched_barrier(0);
    bf16x8 bfr[4][PL], afr[IF][PL];
#pragma unroll
    for (int jj = 0; jj < 4; ++jj)
#pragma unroll
      for (int pl = 0; pl < PL; ++pl)
        bfr[jj][pl] = *(const bf16x8*)&Bs[cb][pl][wn + jj * 16 + lr][gs];
#pragma unroll
    for (int i = 0; i < IF; ++i)
#pragma unroll
      for (int pl = 0; pl < PL; ++pl)
        afr[i][pl] = *(const bf16x8*)&As[cb][pl][wm + i * 16 + lr][gs];
    asm volatile("s_waitcnt lgkmcnt(0)" ::: "memory");   // my reads complete
    __builtin_amdgcn_sched_barrier(0);
    __builtin_amdgcn_s_barrier();              // all waves done reading buf cb
    __builtin_amdgcn_sched_barrier(0);
    if (t + 2 < NTk) ISSUE(cb, (t + 2) << 5);  // overwrite cb; loads fly under MFMA
#pragma unroll
    for (int i = 0; i < IF; ++i)
#pragma unroll
      for (int jj = 0; jj < 4; ++jj) {
        f32x4 a2 = acc[i][jj];
        a2 = __builtin_amdgcn_mfma_f32_16x16x32_bf16(afr[i][0], bfr[jj][0], a2, 0, 0, 0);
        if (NT == 3) {
          a2 = __builtin_amdgcn_mfma_f32_16x16x32_bf16(afr[i][0], bfr[jj][1], a2, 0, 0, 0);
          a2 = __builtin_amdgcn_mfma_f32_16x16x32_bf16(afr[i][1], bfr[jj][0], a2, 0, 0, 0);
        }
        acc[i][jj] = a2;
      }
  }

  // ---- output routing (block-uniform; 128 % ldc-segment == 0 everywhere) ----
  void *O1 = C1, *O2 = C2;
  bool otrans = (OM == 4);
  int coff = 0;
  if (OM == 5) {
    int seg = n0 / ldc;
    coff = seg * ldc;
    if (seg == 1)      { O1 = C3; O2 = C4; }
    else if (seg == 2) { O1 = C5; O2 = C6; otrans = true; }
  } else if (OM == 6) {
    int seg = n0 / ldc;
    coff = seg * ldc;
    if (seg) O1 = C3;
  }

  const int r0 = g * 4;
#pragma unroll
  for (int i = 0; i < IF; ++i) {
    int lrow0 = m0 + wm + i * 16 + r0;
#pragma unroll
    for (int j = 0; j < 4; ++j) {
      int col = n0 + wn + j * 16 + lr - coff;
      if (OM == 4 || (OM == 5 && otrans)) {
        bf16x4 ph, pl;
#pragma unroll
        for (int r = 0; r < 4; ++r) { bf16 hb, lb; split1(acc[i][j][r], hb, lb); ph[r] = hb; pl[r] = lb; }
        *(bf16x4*)&((bf16*)O1)[(size_t)col * ldc + lrow0] = ph;
        *(bf16x4*)&((bf16*)O2)[(size_t)col * ldc + lrow0] = pl;
      } else {
#pragma unroll
        for (int r = 0; r < 4; ++r) {
          int lrow = lrow0 + r;
          if (EXPERT && lrow >= m_count) continue;
          size_t off = (size_t)(row_base + lrow) * ldc + col;
          if (OM == 1 || OM == 6) {
            ((float*)O1)[off] = acc[i][j][r];
          } else {  // OM == 3 or OM == 5 row-major planes
            bf16 hb, lb; split1(acc[i][j][r], hb, lb);
            ((bf16*)O1)[off] = hb;
            ((bf16*)O2)[off] = lb;
          }
        }
      }
    }
  }
}

// ------------------------------------ split-precision flash attention -------
// grid (T/32, H); block = 4 waves; 32 q rows per block as two 16-row tiles A/B.
// Waves split the key range with private (m,l,O) per q-tile; K/V fragments
// loaded once per key-tile and reused for both q-tiles. Swapped QK^T.
__launch_bounds__(256)
__global__ void k_attns(const bf16* __restrict__ Qh, const bf16* __restrict__ Ql,
                        const bf16* __restrict__ Kh, const bf16* __restrict__ Kl,
                        const bf16* __restrict__ Vh, const bf16* __restrict__ Vl,
                        bf16* __restrict__ Oh, bf16* __restrict__ Ol)
{
  const int tid = threadIdx.x;
  const int lane = tid & 63, wid = tid >> 6;
  const int head = blockIdx.y;
  const int qbase = (gridDim.x - 1 - blockIdx.x) * 32;
  const int lr = lane & 15, g = lane >> 4;

  __shared__ float o_l[4][16][132];
  __shared__ float m_l[4][16], l_l[4][16];
  bf16* plbase = (bf16*)&o_l[0][0][0];
  bf16 (*pl_h)[40] = (bf16(*)[40])(plbase + wid * 16 * 40);
  bf16 (*pl_l)[40] = (bf16(*)[40])(plbase + (4 + wid) * 16 * 40);

  bf16x8 qfhA[4], qflA[4], qfhB[4], qflB[4];
  {
    size_t qoffA = (size_t)(qbase + lr) * DD + head * HDIM;
    size_t qoffB = qoffA + (size_t)16 * DD;
#pragma unroll
    for (int c = 0; c < 4; ++c) {
      qfhA[c] = *(const bf16x8*)(Qh + qoffA + c * 32 + g * 8);
      qflA[c] = *(const bf16x8*)(Ql + qoffA + c * 32 + g * 8);
      qfhB[c] = *(const bf16x8*)(Qh + qoffB + c * 32 + g * 8);
      qflB[c] = *(const bf16x8*)(Ql + qoffB + c * 32 + g * 8);
    }
  }

  f32x4 oA[8], oB[8];
#pragma unroll
  for (int d = 0; d < 8; ++d) {
    oA[d] = (f32x4){0.f, 0.f, 0.f, 0.f};
    oB[d] = (f32x4){0.f, 0.f, 0.f, 0.f};
  }
  float mA = -1e30f, lA = 0.f;
  float mB = -1e30f, lB = 0.f;

  const int qend = qbase + 32;
  for (int kb = wid * 32; kb < qend; kb += 128) {
    f32x4 sA0 = {0.f,0.f,0.f,0.f}, sA1 = {0.f,0.f,0.f,0.f};
    f32x4 sB0 = {0.f,0.f,0.f,0.f}, sB1 = {0.f,0.f,0.f,0.f};
    size_t k0off = (size_t)(kb + lr) * DD + head * HDIM;
    size_t k1off = k0off + (size_t)16 * DD;
#pragma unroll
    for (int c = 0; c < 4; ++c) {
      bf16x8 kh0 = *(const bf16x8*)(Kh + k0off + c * 32 + g * 8);
      bf16x8 kl0 = *(const bf16x8*)(Kl + k0off + c * 32 + g * 8);
      sA0 = __builtin_amdgcn_mfma_f32_16x16x32_bf16(kh0, qfhA[c], sA0, 0, 0, 0);
      sA0 = __builtin_amdgcn_mfma_f32_16x16x32_bf16(kl0, qfhA[c], sA0, 0, 0, 0);
      sA0 = __builtin_amdgcn_mfma_f32_16x16x32_bf16(kh0, qflA[c], sA0, 0, 0, 0);
      sB0 = __builtin_amdgcn_mfma_f32_16x16x32_bf16(kh0, qfhB[c], sB0, 0, 0, 0);
      sB0 = __builtin_amdgcn_mfma_f32_16x16x32_bf16(kl0, qfhB[c], sB0, 0, 0, 0);
      sB0 = __builtin_amdgcn_mfma_f32_16x16x32_bf16(kh0, qflB[c], sB0, 0, 0, 0);
      bf16x8 kh1 = *(const bf16x8*)(Kh + k1off + c * 32 + g * 8);
      bf16x8 kl1 = *(const bf16x8*)(Kl + k1off + c * 32 + g * 8);
      sA1 = __builtin_amdgcn_mfma_f32_16x16x32_bf16(kh1, qfhA[c], sA1, 0, 0, 0);
      sA1 = __builtin_amdgcn_mfma_f32_16x16x32_bf16(kl1, qfhA[c], sA1, 0, 0, 0);
      sA1 = __builtin_amdgcn_mfma_f32_16x16x32_bf16(kh1, qflA[c], sA1, 0, 0, 0);
      sB1 = __builtin_amdgcn_mfma_f32_16x16x32_bf16(kh1, qfhB[c], sB1, 0, 0, 0);
      sB1 = __builtin_amdgcn_mfma_f32_16x16x32_bf16(kl1, qfhB[c], sB1, 0, 0, 0);
      sB1 = __builtin_amdgcn_mfma_f32_16x16x32_bf16(kh1, qflB[c], sB1, 0, 0, 0);
    }
    float p0A[4], p1A[4];
    {
      float mloc = -1e30f;
      const int q = qbase + lr;
#pragma unroll
      for (int r = 0; r < 4; ++r) {
        int k0i = kb + g * 4 + r;
        float a0 = sA0[r] * 0.08838834764831845f;
        float a1 = sA1[r] * 0.08838834764831845f;
        if (k0i > q)      a0 = -1e30f;
        if (k0i + 16 > q) a1 = -1e30f;
        p0A[r] = a0; p1A[r] = a1;
        mloc = fmaxf(mloc, fmaxf(a0, a1));
      }
      mloc = fmaxf(mloc, __shfl_xor(mloc, 16, 64));
      mloc = fmaxf(mloc, __shfl_xor(mloc, 32, 64));
      float mn = fmaxf(mA, mloc);
      float alpha = __expf(mA - mn);
      mA = mn;
      float ps = 0.f;
#pragma unroll
      for (int r = 0; r < 4; ++r) {
        p0A[r] = __expf(p0A[r] - mn);
        p1A[r] = __expf(p1A[r] - mn);
        ps += p0A[r] + p1A[r];
      }
      ps += __shfl_xor(ps, 16, 64);
      ps += __shfl_xor(ps, 32, 64);
      lA = lA * alpha + ps;
      float alr[4];
#pragma unroll
      for (int r = 0; r < 4; ++r) alr[r] = __shfl(alpha, g * 4 + r, 64);
#pragma unroll
      for (int d = 0; d < 8; ++d)
#pragma unroll
        for (int r = 0; r < 4; ++r) oA[d][r] *= alr[r];
    }
    float p0B[4], p1B[4];
    {
      float mloc = -1e30f;
      const int q = qbase + 16 + lr;
#pragma unroll
      for (int r = 0; r < 4; ++r) {
        int k0i = kb + g * 4 + r;
        float a0 = sB0[r] * 0.08838834764831845f;
        float a1 = sB1[r] * 0.08838834764831845f;
        if (k0i > q)      a0 = -1e30f;
        if (k0i + 16 > q) a1 = -1e30f;
        p0B[r] = a0; p1B[r] = a1;
        mloc = fmaxf(mloc, fmaxf(a0, a1));
      }
      mloc = fmaxf(mloc, __shfl_xor(mloc, 16, 64));
      mloc = fmaxf(mloc, __shfl_xor(mloc, 32, 64));
      float mn = fmaxf(mB, mloc);
      float alpha = __expf(mB - mn);
      mB = mn;
      float ps = 0.f;
#pragma unroll
      for (int r = 0; r < 4; ++r) {
        p0B[r] = __expf(p0B[r] - mn);
        p1B[r] = __expf(p1B[r] - mn);
        ps += p0B[r] + p1B[r];
      }
      ps += __shfl_xor(ps, 16, 64);
      ps += __shfl_xor(ps, 32, 64);
      lB = lB * alpha + ps;
      float alr[4];
#pragma unroll
      for (int r = 0; r < 4; ++r) alr[r] = __shfl(alpha, g * 4 + r, 64);
#pragma unroll
      for (int d = 0; d < 8; ++d)
#pragma unroll
        for (int r = 0; r < 4; ++r) oB[d][r] *= alr[r];
    }
#pragma unroll
    for (int r = 0; r < 4; ++r) {
      bf16 hb, lb;
      split1(p0A[r], hb, lb);
      pl_h[lr][g * 4 + r] = hb;
      pl_l[lr][g * 4 + r] = lb;
      split1(p1A[r], hb, lb);
      pl_h[lr][16 + g * 4 + r] = hb;
      pl_l[lr][16 + g * 4 + r] = lb;
    }
    bf16x8 pahA = *(const bf16x8*)&pl_h[lr][g * 8];
    bf16x8 palA = *(const bf16x8*)&pl_l[lr][g * 8];
#pragma unroll
    for (int r = 0; r < 4; ++r) {
      bf16 hb, lb;
      split1(p0B[r], hb, lb);
      pl_h[lr][g * 4 + r] = hb;
      pl_l[lr][g * 4 + r] = lb;
      split1(p1B[r], hb, lb);
      pl_h[lr][16 + g * 4 + r] = hb;
      pl_l[lr][16 + g * 4 + r] = lb;
    }
    bf16x8 pahB = *(const bf16x8*)&pl_h[lr][g * 8];
    bf16x8 palB = *(const bf16x8*)&pl_l[lr][g * 8];
#pragma unroll
    for (int d = 0; d < 8; ++d) {
      size_t voff = (size_t)(head * HDIM + d * 16 + lr) * TT + kb + g * 8;
      bf16x8 vfh = *(const bf16x8*)(Vh + voff);
      bf16x8 vfl = *(const bf16x8*)(Vl + voff);
      oA[d] = __builtin_amdgcn_mfma_f32_16x16x32_bf16(pahA, vfh, oA[d], 0, 0, 0);
      oA[d] = __builtin_amdgcn_mfma_f32_16x16x32_bf16(pahA, vfl, oA[d], 0, 0, 0);
      oA[d] = __builtin_amdgcn_mfma_f32_16x16x32_bf16(palA, vfh, oA[d], 0, 0, 0);
      oB[d] = __builtin_amdgcn_mfma_f32_16x16x32_bf16(pahB, vfh, oB[d], 0, 0, 0);
      oB[d] = __builtin_amdgcn_mfma_f32_16x16x32_bf16(pahB, vfl, oB[d], 0, 0, 0);
      oB[d] = __builtin_amdgcn_mfma_f32_16x16x32_bf16(palB, vfh, oB[d], 0, 0, 0);
    }
  }

  __syncthreads();
  if (g == 0) {
    m_l[wid][lr] = mA;
    l_l[wid][lr] = lA;
  }
#pragma unroll
  for (int d = 0; d < 8; ++d)
#pragma unroll
    for (int r = 0; r < 4; ++r)
      o_l[wid][g * 4 + r][d * 16 + lr] = oA[d][r];
  __syncthreads();
  {
    const int row = tid >> 4;
    const int c0 = (tid & 15) * 8;
    float m0v = m_l[0][row], m1v = m_l[1][row], m2v = m_l[2][row], m3v = m_l[3][row];
    float ms = fmaxf(fmaxf(m0v, m1v), fmaxf(m2v, m3v));
    float s0v = __expf(m0v - ms), s1v = __expf(m1v - ms);
    float s2v = __expf(m2v - ms), s3v = __expf(m3v - ms);
    float lsum = l_l[0][row] * s0v + l_l[1][row] * s1v
               + l_l[2][row] * s2v + l_l[3][row] * s3v;
    float inv = 1.f / lsum;
    union { bf16 b[8]; uint4 u; } ph, pl;
#pragma unroll
    for (int j = 0; j < 8; ++j) {
      float v = o_l[0][row][c0 + j] * s0v + o_l[1][row][c0 + j] * s1v
              + o_l[2][row][c0 + j] * s2v + o_l[3][row][c0 + j] * s3v;
      bf16 hb, lb;
      split1(v * inv, hb, lb);
      ph.b[j] = hb; pl.b[j] = lb;
    }
    size_t oi = (size_t)(qbase + row) * DD + head * HDIM + c0;
    *(uint4*)(Oh + oi) = ph.u;
    *(uint4*)(Ol + oi) = pl.u;
  }
  __syncthreads();
  if (g == 0) {
    m_l[wid][lr] = mB;
    l_l[wid][lr] = lB;
  }
#pragma unroll
  for (int d = 0; d < 8; ++d)
#pragma unroll
    for (int r = 0; r < 4; ++r)
      o_l[wid][g * 4 + r][d * 16 + lr] = oB[d][r];
  __syncthreads();
  {
    const int row = tid >> 4;
    const int c0 = (tid & 15) * 8;
    float m0v = m_l[0][row], m1v = m_l[1][row], m2v = m_l[2][row], m3v = m_l[3][row];
    float ms = fmaxf(fmaxf(m0v, m1v), fmaxf(m2v, m3v));
    float s0v = __expf(m0v - ms), s1v = __expf(m1v - ms);
    float s2v = __expf(m2v - ms), s3v = __expf(m3v - ms);
    float lsum = l_l[0][row] * s0v + l_l[1][row] * s1v
               + l_l[2][row] * s2v + l_l[3][row] * s3v;
    float inv = 1.f / lsum;
    union { bf16 b[8]; uint4 u; } ph, pl;
#pragma unroll
    for (int j = 0; j < 8; ++j) {
      float v = o_l[0][row][c0 + j] * s0v + o_l[1][row][c0 + j] * s1v
              + o_l[2][row][c0 + j] * s2v + o_l[3][row][c0 + j] * s3v;
      bf16 hb, lb;
      split1(v * inv, hb, lb);
      ph.b[j] = hb; pl.b[j] = lb;
    }
    size_t oi = (size_t)(qbase + 16 + row) * DD + head * HDIM + c0;
    *(uint4*)(Oh + oi) = ph.u;
    *(uint4*)(Ol + oi) = pl.u;
  }
}

// ------------------------------------------------------------- helpers ------
__global__ void k_embed(const int* __restrict__ ids, const float* __restrict__ Em,
                        float* __restrict__ Hout)
{
  int t = blockIdx.x, tid = threadIdx.x;
  const float4* s = (const float4*)(Em + (size_t)ids[t] * DD);
  float4* dst = (float4*)(Hout + (size_t)t * DD);
  dst[tid] = s[tid];
  dst[tid + 256] = s[tid + 256];
}

template<bool ADDIN, bool WF32, bool FINAL>
__launch_bounds__(256)
__global__ void k_addrms(const float* __restrict__ Hin, float* __restrict__ Res,
                         const float* __restrict__ W,
                         bf16* __restrict__ Xh, bf16* __restrict__ Xl,
                         float* __restrict__ Xf)
{
  const int t = blockIdx.x, tid = threadIdx.x;
  const size_t base = (size_t)t * DD + tid * 8;
  float x[8];
  {
    const float4* hp = (const float4*)(Hin + base);
    float4 a = hp[0], b = hp[1];
    x[0]=a.x; x[1]=a.y; x[2]=a.z; x[3]=a.w;
    x[4]=b.x; x[5]=b.y; x[6]=b.z; x[7]=b.w;
    if (ADDIN) {
      const float4* rp = (const float4*)(Res + base);
      float4 c = rp[0], d = rp[1];
      x[0]+=c.x; x[1]+=c.y; x[2]+=c.z; x[3]+=c.w;
      x[4]+=d.x; x[5]+=d.y; x[6]+=d.z; x[7]+=d.w;
    }
  }
  {
    float4* rp = (float4*)(Res + base);
    rp[0] = make_float4(x[0], x[1], x[2], x[3]);
    rp[1] = make_float4(x[4], x[5], x[6], x[7]);
  }
  float ss = 0.f;
#pragma unroll
  for (int j = 0; j < 8; ++j) ss += x[j] * x[j];
#pragma unroll
  for (int off = 32; off; off >>= 1) ss += __shfl_xor(ss, off, 64);
  __shared__ float red[4];
  if ((tid & 63) == 0) red[tid >> 6] = ss;
  __syncthreads();
  float tot = red[0] + red[1] + red[2] + red[3];
  float sc = rsqrtf(tot * (1.0f / DD) + 1e-6f);
  float y[8];
#pragma unroll
  for (int j = 0; j < 8; ++j) y[j] = x[j] * sc * W[tid * 8 + j];
  if (!FINAL) {
    union { bf16 b[8]; uint4 u; } ph, pl;
#pragma unroll
    for (int j = 0; j < 8; ++j) { bf16 hb, lb; split1(y[j], hb, lb); ph.b[j] = hb; pl.b[j] = lb; }
    *(uint4*)(Xh + base) = ph.u;
    *(uint4*)(Xl + base) = pl.u;
  }
  if (WF32 || FINAL) {
    float4* xp = (float4*)(Xf + base);
    xp[0] = make_float4(y[0], y[1], y[2], y[3]);
    xp[1] = make_float4(y[4], y[5], y[6], y[7]);
  }
}

__global__ void k_rope2(bf16* __restrict__ Qh, bf16* __restrict__ Ql,
                        bf16* __restrict__ Kh, bf16* __restrict__ Kl,
                        const int* __restrict__ pos)
{
  int idx = blockIdx.x * 256 + threadIdx.x;
  int d = idx & 63;
  int h = (idx >> 6) & (HH - 1);
  int t = idx >> 10;
  if (t >= TT) return;
  double inv = pow(1.0e6, -(double)d / 64.0);
  double ang = (double)pos[t] * inv;
  double sd, cd;
  sincos(ang, &sd, &cd);
  float sn = (float)sd, cs = (float)cd;
  size_t base = (size_t)t * DD + h * HDIM + d;
  float q1 = (float)Qh[base] + (float)Ql[base];
  float q2 = (float)Qh[base + 64] + (float)Ql[base + 64];
  float qa = q1 * cs - q2 * sn, qb = q1 * sn + q2 * cs;
  bf16 hb, lb;
  split1(qa, hb, lb); Qh[base] = hb;      Ql[base] = lb;
  split1(qb, hb, lb); Qh[base + 64] = hb; Ql[base + 64] = lb;
  float k1 = (float)Kh[base] + (float)Kl[base];
  float k2 = (float)Kh[base + 64] + (float)Kl[base + 64];
  float ka = k1 * cs - k2 * sn, kb2 = k1 * sn + k2 * cs;
  split1(ka, hb, lb);  Kh[base] = hb;      Kl[base] = lb;
  split1(kb2, hb, lb); Kh[base + 64] = hb; Kl[base + 64] = lb;
}

__launch_bounds__(64)
__global__ void k_router(const float* __restrict__ Xf, const float* __restrict__ RW,
                         const float* __restrict__ SGW, int* __restrict__ eidx,
                         float* __restrict__ ew, float* __restrict__ sgate,
                         int* __restrict__ cnt)
{
  const int t = blockIdx.x, lane = threadIdx.x;
  const float* x = Xf + (size_t)t * DD;
  float acc[8] = {0,0,0,0,0,0,0,0};
  float sg = 0.f;
  for (int i = lane; i < DD; i += 64) {
    float xv = x[i];
    const float4* w = (const float4*)(RW + (size_t)i * NE);
    float4 w0 = w[0], w1 = w[1];
    acc[0] += xv * w0.x; acc[1] += xv * w0.y; acc[2] += xv * w0.z; acc[3] += xv * w0.w;
    acc[4] += xv * w1.x; acc[5] += xv * w1.y; acc[6] += xv * w1.z; acc[7] += xv * w1.w;
    sg += xv * SGW[i];
  }
#pragma unroll
  for (int off = 32; off; off >>= 1) {
#pragma unroll
    for (int e = 0; e < 8; ++e) acc[e] += __shfl_xor(acc[e], off, 64);
    sg += __shfl_xor(sg, off, 64);
  }
  if (lane == 0) {
    int i0 = 0; float v0 = acc[0];
    for (int e = 1; e < 8; ++e) if (acc[e] > v0) { v0 = acc[e]; i0 = e; }
    int i1 = -1; float v1 = -1e30f;
    for (int e = 0; e < 8; ++e) if (e != i0 && acc[e] > v1) { v1 = acc[e]; i1 = e; }
    float w0 = 1.f / (1.f + expf(v1 - v0));
    eidx[2*t] = i0; eidx[2*t+1] = i1;
    ew[2*t] = w0; ew[2*t+1] = 1.f - w0;
    sgate[t] = 1.f / (1.f + expf(-sg));
    atomicAdd(&cnt[i0], 1);
    atomicAdd(&cnt[i1], 1);
  }
}

__global__ void k_scan(const int* __restrict__ cnt, int* __restrict__ ofs)
{
  if (threadIdx.x == 0) {
    int s = 0;
    for (int e = 0; e < NE; ++e) { ofs[e] = s; s += cnt[e]; }
    ofs[NE] = s;
  }
}

__global__ void k_assign(const int* __restrict__ eidx, const int* __restrict__ ofs,
                         int* __restrict__ cursor, int* __restrict__ perm,
                         int* __restrict__ posof)
{
  int t = blockIdx.x * 256 + threadIdx.x;
  if (t >= TT) return;
#pragma unroll
  for (int j = 0; j < 2; ++j) {
    int e = eidx[2*t + j];
    int p = ofs[e] + atomicAdd(&cursor[e], 1);
    perm[p] = t;
    posof[2*t + j] = p;
  }
}

// silu(g)*u from f32 inputs -> bf16 hi/lo planes
__global__ void k_silup(const float* __restrict__ G, const float* __restrict__ U,
                        bf16* __restrict__ H, bf16* __restrict__ L)
{
  int i = (blockIdx.x * 256 + threadIdx.x) * 4;
  float4 g = *(const float4*)(G + i);
  float4 u = *(const float4*)(U + i);
  float s[4];
  s[0] = g.x / (1.f + expf(-g.x)) * u.x;
  s[1] = g.y / (1.f + expf(-g.y)) * u.y;
  s[2] = g.z / (1.f + expf(-g.z)) * u.z;
  s[3] = g.w / (1.f + expf(-g.w)) * u.w;
  bf16x4 h, l;
#pragma unroll
  for (int j = 0; j < 4; ++j) { bf16 hb, lb; split1(s[j], hb, lb); h[j] = hb; l[j] = lb; }
  *(bf16x4*)(H + i) = h;
  *(bf16x4*)(L + i) = l;
}

__global__ void k_combine(const float* __restrict__ Y, const float* __restrict__ SH,
                          const float* __restrict__ sgate, const float* __restrict__ ew,
                          const int* __restrict__ posof, float* __restrict__ Hout)
{
  int t = blockIdx.x, tid = threadIdx.x;
  int p0 = posof[2*t], p1 = posof[2*t+1];
  float w0 = ew[2*t], w1 = ew[2*t+1];
  float sgv = sgate[t];
  int d0 = tid * 8;
  const float4* a = (const float4*)(Y + (size_t)p0 * DD + d0);
  const float4* b = (const float4*)(Y + (size_t)p1 * DD + d0);
  float4 a0 = a[0], a1 = a[1], b0 = b[0], b1 = b[1];
  float y0[8] = {a0.x,a0.y,a0.z,a0.w,a1.x,a1.y,a1.z,a1.w};
  float y1[8] = {b0.x,b0.y,b0.z,b0.w,b1.x,b1.y,b1.z,b1.w};
  const float4* shp = (const float4*)(SH + (size_t)t * DD + d0);
  float4 sa = shp[0], sb = shp[1];
  float shv[8] = {sa.x, sa.y, sa.z, sa.w, sb.x, sb.y, sb.z, sb.w};
  float out[8];
#pragma unroll
  for (int j = 0; j < 8; ++j)
    out[j] = (y0[j] * w0 + y1[j] * w1 + sgv * shv[j]) * 0.70710678118654752f;
  float4* op = (float4*)(Hout + (size_t)t * DD + d0);
  op[0] = make_float4(out[0], out[1], out[2], out[3]);
  op[1] = make_float4(out[4], out[5], out[6], out[7]);
}

// -------------------------------------------------------------- driver ------
extern "C" void kernel_launch(void* const* d_in, const int* in_sizes, int n_in,
                              void* d_out, int out_size, void* d_ws, size_t ws_size,
                              hipStream_t stream)
{
  (void)in_sizes; (void)n_in; (void)out_size; (void)ws_size;
  const int*   ids  = (const int*)d_in[0];
  const int*   pos  = (const int*)d_in[1];
  const float* emb  = (const float*)d_in[2];
  const float* qw   = (const float*)d_in[3];
  const float* kw   = (const float*)d_in[4];
  const float* vw   = (const float*)d_in[5];
  const float* ow   = (const float*)d_in[6];
  const float* ln1  = (const float*)d_in[7];
  const float* ln2  = (const float*)d_in[8];
  const float* rw   = (const float*)d_in[9];
  const float* sgw  = (const float*)d_in[10];
  const float* wg   = (const float*)d_in[11];
  const float* wu   = (const float*)d_in[12];
  const float* wd   = (const float*)d_in[13];
  const float* swg  = (const float*)d_in[14];
  const float* swu  = (const float*)d_in[15];
  const float* swd  = (const float*)d_in[16];
  const float* fln  = (const float*)d_in[17];

  char* p = (char*)d_ws;
  auto alloc = [&](size_t b) { char* r = p; p += (b + 255) & ~(size_t)255; return r; };

  const size_t TD = (size_t)TT * DD;
  float* resid = (float*)alloc(TD * 4);
  float* hbuf  = (float*)alloc(TD * 4);
  float* xf    = (float*)alloc(TD * 4);
  bf16*  xh    = (bf16*) alloc(TD * 2);
  bf16*  xl    = (bf16*) alloc(TD * 2);
  bf16*  qhb   = (bf16*) alloc(TD * 2);
  bf16*  qlb   = (bf16*) alloc(TD * 2);
  bf16*  khb   = (bf16*) alloc(TD * 2);
  bf16*  klb   = (bf16*) alloc(TD * 2);
  bf16*  vth   = (bf16*) alloc(TD * 2);
  bf16*  vtl   = (bf16*) alloc(TD * 2);
  bf16*  aoh   = (bf16*) alloc(TD * 2);
  bf16*  aol   = (bf16*) alloc(TD * 2);
  float* shb   = (float*)alloc(TD * 4);
  const size_t SGF = (size_t)TT * FSS;
  const size_t GEF = (size_t)TT * TOPK * FF;
  bf16*  shph  = (bf16*) alloc(SGF * 2);
  bf16*  shpl  = (bf16*) alloc(SGF * 2);
  bf16*  geph  = (bf16*) alloc(GEF * 2);
  bf16*  gepl  = (bf16*) alloc(GEF * 2);
  float* region = (float*)alloc(2 * SGF * 4);
  float* sgbf = region;
  float* subf = region + SGF;
  float* gebf = region;
  float* uebf = region + GEF;
  float* ybf  = region + 2 * GEF;
  const size_t WME = (size_t)NE * DD * FF;
  bf16* wbh = (bf16*)alloc(WME * 2);
  bf16* wbl = (bf16*)alloc(WME * 2);
  int*   eidx  = (int*)  alloc((size_t)TT * TOPK * 4);
  float* ewb   = (float*)alloc((size_t)TT * TOPK * 4);
  float* sgate = (float*)alloc((size_t)TT * 4);
  int*   perm  = (int*)  alloc((size_t)TT * TOPK * 4);
  int*   posof = (int*)  alloc((size_t)TT * TOPK * 4);
  int*   cnt   = (int*)  alloc(64);
  int*   ofs   = (int*)  alloc(64);
  int*   cursor = cnt + 8;

  k_embed<<<TT, 256, 0, stream>>>(ids, emb, hbuf);

  for (int l = 0; l < NL; ++l) {
    const float* qw_l  = qw  + (size_t)l * DD * DD;
    const float* kw_l  = kw  + (size_t)l * DD * DD;
    const float* vw_l  = vw  + (size_t)l * DD * DD;
    const float* ow_l  = ow  + (size_t)l * DD * DD;
    const float* ln1_l = ln1 + (size_t)l * DD;
    const float* ln2_l = ln2 + (size_t)l * DD;
    const float* rw_l  = rw  + (size_t)l * DD * NE;
    const float* sgw_l = sgw + (size_t)l * DD;
    const float* wg_l  = wg  + (size_t)l * NE * DD * FF;
    const float* wu_l  = wu  + (size_t)l * NE * DD * FF;
    const float* wd_l  = wd  + (size_t)l * NE * FF * DD;
    const float* swg_l = swg + (size_t)l * DD * FSS;
    const float* swu_l = swu + (size_t)l * DD * FSS;
    const float* swd_l = swd + (size_t)l * FSS * DD;
    const bool last = (l == NL - 1);

    if (l == 0)
      k_addrms<false,false,false><<<TT,256,0,stream>>>(hbuf, resid, ln1_l, xh, xl, nullptr);
    else
      k_addrms<true, false,false><<<TT,256,0,stream>>>(hbuf, resid, ln1_l, xh, xl, nullptr);

    // ---- attention: fused QKV (B = concat along N), then rope/attn/O ----
    k_wtrans<true><<<dim3(32,32),256,0,stream>>>(qw_l, wbh, wbl, DD, DD, 0,    3*DD);
    k_wtrans<true><<<dim3(32,32),256,0,stream>>>(kw_l, wbh, wbl, DD, DD, DD,   3*DD);
    k_wtrans<true><<<dim3(32,32),256,0,stream>>>(vw_l, wbh, wbl, DD, DD, 2*DD, 3*DD);
    k_gemmp<128,3,false,false,5><<<dim3(16,48),256,0,stream>>>(xh, xl, wbh, wbl,
        qhb, qlb, khb, klb, vth, vtl, TT, 3*DD, DD, DD, DD, nullptr,nullptr,nullptr);
    k_rope2<<<(TT*HH*64)/256, 256, 0, stream>>>(qhb, qlb, khb, klb, pos);
    k_attns<<<dim3(TT/32, HH), 256, 0, stream>>>(qhb, qlb, khb, klb, vth, vtl, aoh, aol);
    k_wtrans<true><<<dim3(32,32),256,0,stream>>>(ow_l, wbh, wbl, DD, DD, 0, DD);
    k_gemmp<128,3,false,false,1><<<dim3(16,16),256,0,stream>>>(aoh, aol, wbh, wbl,
        hbuf, nullptr, nullptr, nullptr, nullptr, nullptr, TT, DD, DD, DD, DD, nullptr,nullptr,nullptr);

    k_addrms<true,true,false><<<TT,256,0,stream>>>(hbuf, resid, ln2_l, xh, xl, xf);

    hipMemsetAsync(cnt, 0, 64, stream);
    k_router<<<TT, 64, 0, stream>>>(xf, rw_l, sgw_l, eidx, ewb, sgate, cnt);
    k_scan<<<1, 64, 0, stream>>>(cnt, ofs);
    k_assign<<<TT/256, 256, 0, stream>>>(eidx, ofs, cursor, perm, posof);

    // ---- shared expert: fused swg+swu, silu, swd ----
    if (!last) {
      k_wtrans<true><<<dim3(32,88),256,0,stream>>>(swg_l, wbh, wbl, DD, FSS, 0,   2*FSS);
      k_wtrans<true><<<dim3(32,88),256,0,stream>>>(swu_l, wbh, wbl, DD, FSS, FSS, 2*FSS);
      k_gemmp<128,3,false,false,6><<<dim3(16,88),256,0,stream>>>(xh, xl, wbh, wbl,
          sgbf, nullptr, subf, nullptr, nullptr, nullptr, TT, 2*FSS, DD, DD, FSS, nullptr,nullptr,nullptr);
      k_silup<<<(TT*FSS/4)/256, 256, 0, stream>>>(sgbf, subf, shph, shpl);
      k_wtrans<true><<<dim3(88,32),256,0,stream>>>(swd_l, wbh, wbl, FSS, DD, 0, DD);
      k_gemmp<128,3,false,false,1><<<dim3(16,16),256,0,stream>>>(shph, shpl, wbh, wbl,
          shb, nullptr, nullptr, nullptr, nullptr, nullptr, TT, DD, FSS, FSS, DD, nullptr,nullptr,nullptr);
    } else {
      k_wtrans<false><<<dim3(32,88),256,0,stream>>>(swg_l, wbh, wbl, DD, FSS, 0,   2*FSS);
      k_wtrans<false><<<dim3(32,88),256,0,stream>>>(swu_l, wbh, wbl, DD, FSS, FSS, 2*FSS);
      k_gemmp<128,1,false,false,6><<<dim3(16,88),256,0,stream>>>(xh, xl, wbh, wbl,
          sgbf, nullptr, subf, nullptr, nullptr, nullptr, TT, 2*FSS, DD, DD, FSS, nullptr,nullptr,nullptr);
      k_silup<<<(TT*FSS/4)/256, 256, 0, stream>>>(sgbf, subf, shph, shpl);
      k_wtrans<false><<<dim3(88,32),256,0,stream>>>(swd_l, wbh, wbl, FSS, DD, 0, DD);
      k_gemmp<128,1,false,false,1><<<dim3(16,16),256,0,stream>>>(shph, shpl, wbh, wbl,
          shb, nullptr, nullptr, nullptr, nullptr, nullptr, TT, DD, FSS, FSS, DD, nullptr,nullptr,nullptr);
    }

    // ---- routed experts (BMT=128: 4 x-blocks/expert -> halved B re-fetch;
    //      grid.x=16 covers max cnt[e]=2048; natural block ids) ----
    if (!last) {
      k_wtrans<true><<<dim3(32,22,NE),256,0,stream>>>(wg_l, wbh, wbl, DD, FF, 0, FF);
      k_gemmp<128,3,true,true,1><<<dim3(16,11,NE),256,0,stream>>>(xh, xl, wbh, wbl,
          gebf, nullptr, nullptr, nullptr, nullptr, nullptr, TT, FF, DD, DD, FF, perm, cnt, ofs);
      k_wtrans<true><<<dim3(32,22,NE),256,0,stream>>>(wu_l, wbh, wbl, DD, FF, 0, FF);
      k_gemmp<128,3,true,true,1><<<dim3(16,11,NE),256,0,stream>>>(xh, xl, wbh, wbl,
          uebf, nullptr, nullptr, nullptr, nullptr, nullptr, TT, FF, DD, DD, FF, perm, cnt, ofs);
      k_silup<<<(GEF/4)/256, 256, 0, stream>>>(gebf, uebf, geph, gepl);
      k_wtrans<true><<<dim3(22,32,NE),256,0,stream>>>(wd_l, wbh, wbl, FF, DD, 0, DD);
      k_gemmp<128,3,true,false,1><<<dim3(16,16,NE),256,0,stream>>>(geph, gepl, wbh, wbl,
          ybf, nullptr, nullptr, nullptr, nullptr, nullptr, TT, DD, FF, FF, DD, nullptr, cnt, ofs);
    } else {
      k_wtrans<false><<<dim3(32,22,NE),256,0,stream>>>(wg_l, wbh, wbl, DD, FF, 0, FF);
      k_gemmp<128,1,true,true,1><<<dim3(16,11,NE),256,0,stream>>>(xh, xl, wbh, wbl,
          gebf, nullptr, nullptr, nullptr, nullptr, nullptr, TT, FF, DD, DD, FF, perm, cnt, ofs);
      k_wtrans<false><<<dim3(32,22,NE),256,0,stream>>>(wu_l, wbh, wbl, DD, FF, 0, FF);
      k_gemmp<128,1,true,true,1><<<dim3(16,11,NE),256,0,stream>>>(xh, xl, wbh, wbl,
          uebf, nullptr, nullptr, nullptr, nullptr, nullptr, TT, FF, DD, DD, FF, perm, cnt, ofs);
      k_silup<<<(GEF/4)/256, 256, 0, stream>>>(gebf, uebf, geph, gepl);
      k_wtrans<false><<<dim3(22,32,NE),256,0,stream>>>(wd_l, wbh, wbl, FF, DD, 0, DD);
      k_gemmp<128,1,true,false,1><<<dim3(16,16,NE),256,0,stream>>>(geph, gepl, wbh, wbl,
          ybf, nullptr, nullptr, nullptr, nullptr, nullptr, TT, DD, FF, FF, DD, nullptr, cnt, ofs);
    }
    k_combine<<<TT, 256, 0, stream>>>(ybf, shb, sgate, ewb, posof, hbuf);
  }

  k_addrms<true,false,true><<<TT,256,0,stream>>>(hbuf, resid, fln, nullptr, nullptr, (float*)d_out);
}